// Round 7
// baseline (406.971 us; speedup 1.0000x reference)
//
#include <hip/hip_runtime.h>
#include <hip/hip_bf16.h>

#define NN 8192
#define CIN 256
#define COUT 128
#define GR 32
#define GKT 64
#define CH 16           // i-chunks
#define ICH (NN / CH)   // 512 rows per chunk
#define KT 64           // i-rows per tile
#define HTS 72          // htS row stride in u16 (144 B: 16B-aligned, bank-balanced)

typedef unsigned short u16;
typedef _Float16 f16;
typedef __attribute__((ext_vector_type(8))) short short8;
typedef __attribute__((ext_vector_type(8))) _Float16 f16x8;
typedef __attribute__((ext_vector_type(16))) float f32x16;

__device__ __forceinline__ short8 pack8_bf16(const float* v) {
    union { __hip_bfloat162 b2[4]; short8 s; } u;
    #pragma unroll
    for (int q = 0; q < 4; ++q)
        u.b2[q] = __float22bfloat162_rn(make_float2(v[2 * q], v[2 * q + 1]));
    return u.s;
}

// ---------------- Kernel A: h = x @ W (fp32) + fused a_src/a_dst ----------
// 32 rows/block, 256 blocks, 4x4 thread tile; epilogue emits bf16 transposed
// h_t[c][i] + a_src/a_dst row dots. (Unchanged from R6.)
__global__ __launch_bounds__(256) void gemm_h(const float* __restrict__ x,
                                              const float* __restrict__ W,
                                              const float* __restrict__ att_src,
                                              const float* __restrict__ att_dst,
                                              u16* __restrict__ h_t,
                                              float* __restrict__ a_src,
                                              float* __restrict__ a_dst) {
    __shared__ float Wt[GKT * COUT];      // 32 KB
    __shared__ float xt[GKT][GR + 4];     // 9 KB
    __shared__ float ot[GR][COUT + 4];    // 16.5 KB
    int tid = threadIdx.x;
    int i0 = blockIdx.x * GR;
    int tx = tid & 31, ty = tid >> 5;
    int c0 = tx * 4, r0 = ty * 4;
    int xr = tid >> 3, xk = (tid & 7) * 8;
    float acc[4][4] = {};

    for (int kt = 0; kt < CIN; kt += GKT) {
        float4 wv[8];
        #pragma unroll
        for (int j = 0; j < 8; ++j) {
            int f = j * 256 + tid;
            wv[j] = *(const float4*)&W[(size_t)(kt + (f >> 5)) * COUT + (f & 31) * 4];
        }
        float4 xv0 = *(const float4*)&x[(size_t)(i0 + xr) * CIN + kt + xk];
        float4 xv1 = *(const float4*)&x[(size_t)(i0 + xr) * CIN + kt + xk + 4];
        __syncthreads();
        #pragma unroll
        for (int j = 0; j < 8; ++j)
            *(float4*)&Wt[(j * 256 + tid) * 4] = wv[j];
        xt[xk + 0][xr] = xv0.x; xt[xk + 1][xr] = xv0.y;
        xt[xk + 2][xr] = xv0.z; xt[xk + 3][xr] = xv0.w;
        xt[xk + 4][xr] = xv1.x; xt[xk + 5][xr] = xv1.y;
        xt[xk + 6][xr] = xv1.z; xt[xk + 7][xr] = xv1.w;
        __syncthreads();
        #pragma unroll 8
        for (int k = 0; k < GKT; ++k) {
            float4 wk = *(const float4*)&Wt[k * COUT + c0];
            float4 xf = *(const float4*)&xt[k][r0];
            float xa[4] = {xf.x, xf.y, xf.z, xf.w};
            #pragma unroll
            for (int a = 0; a < 4; ++a) {
                acc[a][0] += xa[a] * wk.x; acc[a][1] += xa[a] * wk.y;
                acc[a][2] += xa[a] * wk.z; acc[a][3] += xa[a] * wk.w;
            }
        }
    }

    float4 asv = *(const float4*)&att_src[c0];
    float4 adv = *(const float4*)&att_dst[c0];
    #pragma unroll
    for (int a = 0; a < 4; ++a) {
        float4 o = make_float4(acc[a][0], acc[a][1], acc[a][2], acc[a][3]);
        *(float4*)&ot[r0 + a][c0] = o;
        float s = o.x * asv.x + o.y * asv.y + o.z * asv.z + o.w * asv.w;
        float d = o.x * adv.x + o.y * adv.y + o.z * adv.z + o.w * adv.w;
        #pragma unroll
        for (int m = 16; m >= 1; m >>= 1) {
            s += __shfl_xor(s, m, 32);
            d += __shfl_xor(d, m, 32);
        }
        if (tx == 0) {
            a_src[i0 + r0 + a] = s;
            a_dst[i0 + r0 + a] = d;
        }
    }
    __syncthreads();
    int c = tid >> 1, hf = tid & 1;
    float vals[16];
    #pragma unroll
    for (int q = 0; q < 16; ++q) vals[q] = ot[hf * 16 + q][c];
    *(short8*)(h_t + (size_t)c * NN + i0 + hf * 16)     = pack8_bf16(vals);
    *(short8*)(h_t + (size_t)c * NN + i0 + hf * 16 + 8) = pack8_bf16(vals + 8);
}

// ---------------- Kernel B: fused masked-GEMM (MFMA, bitmask A) -----------
// Block = (jb, ch): j-tile 128 (4 waves x 32 j), i-chunk 512. Per 64-i tile:
//  - adj block -> VGPRs (coalesced float4; compiler fine-grained vmcnt, no
//    global_load_lds barrier drain) -> 4 ballots/float4 -> 1 KB LDS bitmask
//    maskS[row][slot] (slot=col&3, bit=col>>2). R6's 32 KB fp32 tileA +
//    32 column ds_read_b32 becomes 1 KB + 8 broadcast b32 reads (2-way=free).
//  - B: h_t tile (128c x 64i bf16) -> LDS stride-72 (unchanged).
// LDS 54->21 KB, launch_bounds(256,3): 3 blocks/CU (12 waves) vs 2.
// A-frag on the fly: p = (bit || i==j) ? exp(lrelu(a_src+a_dst)) : 0.
__global__ __launch_bounds__(256, 3) void gat_mm(const float* __restrict__ adj,
                                                 const u16* __restrict__ h_t,
                                                 const float* __restrict__ a_src,
                                                 const float* __restrict__ a_dst,
                                                 f16* __restrict__ pout,
                                                 float* __restrict__ pden) {
    __shared__ unsigned int maskS[KT * 4];   // 1 KB
    __shared__ u16 htS[128 * HTS];           // 18 KB
    __shared__ float asrcS[ICH];             // 2 KB
    int tid = threadIdx.x;
    int lane = tid & 63, w = tid >> 6;
    int jb = blockIdx.x & 63, ch = blockIdx.x >> 6;
    int j0 = jb * 128;
    int i0 = ch * ICH;
    int half = lane >> 5;
    int jloc = w * 32 + (lane & 31);
    int gj = j0 + jloc;
    int slot = lane & 3;        // == jloc & 3
    int kbit = jloc >> 2;       // bit index within mask word (0..31)
    float dj = a_dst[gj];
    if (tid < ICH / 4)
        ((float4*)asrcS)[tid] = ((const float4*)(a_src + i0))[tid];

    f32x16 acc[4];
    #pragma unroll
    for (int nt = 0; nt < 4; ++nt)
        #pragma unroll
        for (int q = 0; q < 16; ++q) acc[nt][q] = 0.f;
    float dsum = 0.f;
    __syncthreads();

    for (int s = 0; s < ICH / KT; ++s) {
        int ib = i0 + s * KT;
        // adj tile -> regs (coalesced: wave covers 2 full 128-col rows/q)
        float4 v[8];
        #pragma unroll
        for (int q = 0; q < 8; ++q) {
            int f = q * 256 + tid;
            v[q] = *(const float4*)&adj[(size_t)(ib + (f >> 5)) * NN + j0 + (f & 31) * 4];
        }
        // B tile -> regs (128 B segments per c-row)
        short8 bv[4]; int bc[4], bi[4];
        #pragma unroll
        for (int q = 0; q < 4; ++q) {
            int p = q * 256 + tid;
            bc[q] = p >> 3; bi[q] = (p & 7) * 8;
            bv[q] = *(const short8*)(h_t + (size_t)bc[q] * NN + ib + bi[q]);
        }
        // ballots -> bitmask (bit c>>2 of word [row][c&3])
        #pragma unroll
        for (int q = 0; q < 8; ++q) {
            unsigned long long b0 = __ballot(v[q].x != 0.f);
            unsigned long long b1 = __ballot(v[q].y != 0.f);
            unsigned long long b2 = __ballot(v[q].z != 0.f);
            unsigned long long b3 = __ballot(v[q].w != 0.f);
            unsigned long long bb = slot == 0 ? b0 : slot == 1 ? b1
                                  : slot == 2 ? b2 : b3;
            unsigned int mw = (unsigned int)(bb >> (half * 32));
            int R = q * 8 + w * 2 + half;
            if ((lane & 31) < 4) maskS[R * 4 + slot] = mw;   // 8 banks, no conflict
        }
        #pragma unroll
        for (int q = 0; q < 4; ++q)
            *(short8*)(htS + bc[q] * HTS + bi[q]) = bv[q];
        __syncthreads();

        #pragma unroll
        for (int kk = 0; kk < 4; ++kk) {
            int kb = kk * 16 + half * 8;
            int gib = ib + kb;
            short8 bf[4];
            #pragma unroll
            for (int nt = 0; nt < 4; ++nt)
                bf[nt] = *(const short8*)(htS + (nt * 32 + (lane & 31)) * HTS + kb);
            float pv[8];
            #pragma unroll
            for (int e = 0; e < 8; ++e) {
                unsigned int mw = maskS[(kb + e) * 4 + slot];
                float t = asrcS[s * KT + kb + e] + dj;
                float ev = __expf(fmaxf(t, 0.2f * t));       // lrelu then exp
                bool on = ((mw >> kbit) & 1u) | (gib + e == gj);  // + self-loop
                pv[e] = on ? ev : 0.f;
                dsum += pv[e];
            }
            short8 af = pack8_bf16(pv);
            #pragma unroll
            for (int nt = 0; nt < 4; ++nt)
                acc[nt] = __builtin_amdgcn_mfma_f32_32x32x16_bf16(af, bf[nt],
                                                                  acc[nt], 0, 0, 0);
        }
        __syncthreads();
    }

    // partial C (fp16): C/D layout col=lane&31, row=(r&3)+8*(r>>2)+4*half
    #pragma unroll
    for (int nt = 0; nt < 4; ++nt) {
        int c = nt * 32 + (lane & 31);
        #pragma unroll
        for (int r = 0; r < 16; ++r) {
            int row = (r & 3) + 8 * (r >> 2) + 4 * half;
            int j = j0 + w * 32 + row;
            pout[((size_t)ch * NN + j) * COUT + c] = (f16)acc[nt][r];
        }
    }
    float dall = dsum + __shfl_xor(dsum, 32, 64);   // halves cover disjoint i
    if (half == 0) pden[(size_t)ch * NN + gj] = dall;
}

// ---------------- Kernel C: reduce partials, normalize, bias --------------
__global__ __launch_bounds__(256) void gat_reduce(const f16* __restrict__ pout,
                                                  const float* __restrict__ pden,
                                                  const float* __restrict__ bias,
                                                  float* __restrict__ out) {
    int idx = blockIdx.x * 256 + threadIdx.x;
    int j = idx >> 4;
    int c8 = (idx & 15) * 8;
    float den = 0.f;
    #pragma unroll
    for (int ch = 0; ch < CH; ++ch) den += pden[(size_t)ch * NN + j];
    float s[8] = {};
    #pragma unroll
    for (int ch = 0; ch < CH; ++ch) {
        f16x8 pv = *(const f16x8*)(pout + ((size_t)ch * NN + j) * COUT + c8);
        #pragma unroll
        for (int q = 0; q < 8; ++q) s[q] += (float)pv[q];
    }
    float inv = 1.0f / den;
    float4 b0 = *(const float4*)&bias[c8];
    float4 b1 = *(const float4*)&bias[c8 + 4];
    float4 o0 = make_float4(s[0] * inv + b0.x, s[1] * inv + b0.y,
                            s[2] * inv + b0.z, s[3] * inv + b0.w);
    float4 o1 = make_float4(s[4] * inv + b1.x, s[5] * inv + b1.y,
                            s[6] * inv + b1.z, s[7] * inv + b1.w);
    *(float4*)&out[(size_t)j * COUT + c8]     = o0;
    *(float4*)&out[(size_t)j * COUT + c8 + 4] = o1;
}

extern "C" void kernel_launch(void* const* d_in, const int* in_sizes, int n_in,
                              void* d_out, int out_size, void* d_ws, size_t ws_size,
                              hipStream_t stream) {
    const float* x       = (const float*)d_in[0];
    const float* adj     = (const float*)d_in[1];
    const float* W       = (const float*)d_in[2];
    const float* att_src = (const float*)d_in[3];
    const float* att_dst = (const float*)d_in[4];
    const float* bias    = (const float*)d_in[5];
    float* out = (float*)d_out;

    u16*   h_t   = (u16*)d_ws;                                  // 2 MB
    float* a_src = (float*)((char*)d_ws + (size_t)2 * 1024 * 1024);
    float* a_dst = a_src + NN;                                  // 32 KB each
    float* pden  = a_dst + NN;                                  // 512 KB
    f16*   pout  = (f16*)(pden + (size_t)CH * NN);              // 32 MB

    gemm_h    <<<NN / GR, 256, 0, stream>>>(x, W, att_src, att_dst, h_t, a_src, a_dst);
    gat_mm    <<<64 * CH, 256, 0, stream>>>(adj, h_t, a_src, a_dst, pout, pden);
    gat_reduce<<<NN * COUT / 8 / 256, 256, 0, stream>>>(pout, pden, bias, out);
}